// Round 3
// baseline (79.364 us; speedup 1.0000x reference)
//
#include <hip/hip_runtime.h>
#include <hip/hip_fp16.h>

#define NUM_VARS    10000
#define NUM_CLAUSES 100000
#define BATCH       256
#define CPI         8                     // clauses per chunk
#define NCHUNK      (NUM_CLAUSES / CPI)   // 12500 exact
#define WAVES_H     4096                  // waves per batch-half

typedef __attribute__((ext_vector_type(4))) _Float16 half4_t;
typedef __attribute__((ext_vector_type(2))) _Float16 half2_t;
typedef __attribute__((ext_vector_type(4))) float    float4_t;

static __device__ __forceinline__ half2_t h2max(half2_t a, half2_t b) {
    half2_t r;                       // folds to v_pk_max_f16 (no NaN here)
    r.x = (a.x > b.x) ? a.x : b.x;
    r.y = (a.y > b.y) ? a.y : b.y;
    return r;
}
static __device__ __forceinline__ half2_t h2min(half2_t a, half2_t b) {
    half2_t r;                       // folds to v_pk_min_f16
    r.x = (a.x < b.x) ? a.x : b.x;
    r.y = (a.y < b.y) ? a.y : b.y;
    return r;
}

// Kernel 1: fp32 -> fp16 convert into d_ws + init d_out to +inf.
// The harness's 256 MiB ws poison fill is UNCONDITIONAL (measured r1/r2:
// fills run at 41 us/call even with ws untouched), so using ws is free.
// fp16 halves gather traffic; max/min are 1-Lipschitz selections so the
// 2^-12 rounding error doesn't accumulate (r0 measured absmax 2.4e-4).
__global__ __launch_bounds__(256) void fuzzy_convert_init(
    const float4_t* __restrict__ in,    // [NUM_VARS*BATCH/4] fp32
    half4_t*        __restrict__ out16, // same linear layout, fp16
    float*          __restrict__ out)   // [BATCH]
{
    if (blockIdx.x == 0 && threadIdx.x < BATCH)
        out[threadIdx.x] = __uint_as_float(0x7F800000u);  // +inf

    const int n4 = NUM_VARS * BATCH / 4;  // 640000
    for (int i = blockIdx.x * blockDim.x + threadIdx.x; i < n4;
         i += gridDim.x * blockDim.x) {
        float4_t v = in[i];
        half4_t h;
        h.x = (_Float16)v.x;  h.y = (_Float16)v.y;
        h.z = (_Float16)v.z;  h.w = (_Float16)v.w;
        out16[i] = h;
    }
}

// Batch-half split with XCD steering: fp16 footprint per half is
// 10000 x 128 x 2 B = 2.56 MB < 4 MiB per-XCD L2. XCDs 0-3 -> cols 0-127,
// XCDs 4-7 -> cols 128-255. One lane owns a half2 (2 cols): a wave's gather
// is 64 x 4 B = 256 B, one coalesced transaction covering 128 columns.
//
// ILP structure (round-2 win, kept): uniform wave id -> clause metadata via
// s_load_dwordx16 batches; all 24 gathers of an 8-clause chunk in flight
// before first use. Literal transform neg ? 1-x : x == s*x + n with
// s = 1-2n in {+1,-1}: one v_pk_fma_f16; clause max / acc min packed.
__global__ __launch_bounds__(512, 8) void fuzzy_cnf_fp16(
    const half2_t* __restrict__ input16,  // [NUM_VARS, 128] half2
    const int*     __restrict__ lit_idx,  // [NUM_CLAUSES, 3]
    const int*     __restrict__ lit_neg,  // [NUM_CLAUSES, 3]
    float*         __restrict__ out)      // [BATCH]
{
    const int wave   = threadIdx.x >> 6;            // 0..7
    const int lane   = threadIdx.x & 63;
    const int xcd    = blockIdx.x & 7;              // round-robin heuristic
    const int half   = (xcd >= 4) ? 1 : 0;          // batch half
    const int hBlock = ((blockIdx.x >> 3) << 2) | (xcd & 3);       // 0..511
    const int gwave  = __builtin_amdgcn_readfirstlane(hBlock * 8 + wave); // 0..4095
    const int coff   = half * 64 + lane;            // half2 column index

    half2_t acc;
    acc.x = (_Float16)30000.0f;  acc.y = (_Float16)30000.0f;

    #pragma unroll 1   // one chunk's state live (~40 VGPR) -> 8 waves/SIMD
    for (int ch = gwave; ch < NCHUNK; ch += WAVES_H) {
        const int base = ch * (CPI * 3);            // SGPR

        int idx[CPI * 3];
        int neg[CPI * 3];
        #pragma unroll
        for (int j = 0; j < CPI * 3; ++j) idx[j] = lit_idx[base + j];  // s_load
        #pragma unroll
        for (int j = 0; j < CPI * 3; ++j) neg[j] = lit_neg[base + j];  // s_load

        half2_t x[CPI * 3];
        #pragma unroll
        for (int j = 0; j < CPI * 3; ++j)
            x[j] = input16[idx[j] * 128 + coff];    // 256B/wave, L2-resident

        #pragma unroll
        for (int q = 0; q < CPI; ++q) {
            half2_t v[3];
            #pragma unroll
            for (int l = 0; l < 3; ++l) {
                const int j = 3 * q + l;
                const _Float16 s = neg[j] ? (_Float16)-1.0f : (_Float16)1.0f;
                const _Float16 n = neg[j] ? (_Float16)1.0f  : (_Float16)0.0f;
                half2_t sv; sv.x = s; sv.y = s;
                half2_t nv; nv.x = n; nv.y = n;
                v[l] = x[j] * sv + nv;              // v_pk_fma_f16
            }
            acc = h2min(acc, h2max(h2max(v[0], v[1]), v[2]));
        }
    }

    // 8 waves -> partial min per column in LDS, then one device atomicMin per
    // column per block (values >= 0 so float-bit order == uint order).
    __shared__ float sm[8][128];
    sm[wave][lane * 2 + 0] = (float)acc.x;
    sm[wave][lane * 2 + 1] = (float)acc.y;
    __syncthreads();

    const int t = threadIdx.x;
    if (t < 128) {
        float m = sm[0][t];
        #pragma unroll
        for (int w = 1; w < 8; ++w) m = fminf(m, sm[w][t]);
        atomicMin((unsigned int*)out + half * 128 + t, __float_as_uint(m));
    }
}

extern "C" void kernel_launch(void* const* d_in, const int* in_sizes, int n_in,
                              void* d_out, int out_size, void* d_ws, size_t ws_size,
                              hipStream_t stream) {
    const float* input   = (const float*)d_in[0];
    const int*   lit_idx = (const int*)d_in[1];
    const int*   lit_neg = (const int*)d_in[2];
    float*       out     = (float*)d_out;

    half4_t* input16 = (half4_t*)d_ws;  // 5.12 MB << ws_size; fill is free

    fuzzy_convert_init<<<1024, 256, 0, stream>>>((const float4_t*)input,
                                                 input16, out);
    fuzzy_cnf_fp16<<<1024, 512, 0, stream>>>((const half2_t*)input16,
                                             lit_idx, lit_neg, out);
}